// Round 9
// baseline (60.384 us; speedup 1.0000x reference)
//
#include <hip/hip_runtime.h>
#include <hip/hip_bf16.h>
#include <cstdint>

// Problem dims (fixed by reference)
constexpr int B  = 8;
constexpr int LQ = 256;
constexpr int LK = 256;
constexpr int D  = 512;   // Dq == Dk
constexpr int A  = 256;

constexpr float NEG_INF   = -1e15f;               // matches reference -INFINITY
constexpr float LOG2E     = 1.4426950408889634f;
constexpr float TWO_LOG2E = 2.8853900817779268f;  // folded into W at staging

// GEMM tiling (BR 32->16 vs round 8: grid 512->1024, 4 blocks/CU)
constexpr int BR = 16;   // rows per block (q/k rows)
constexpr int BC = 64;   // cols per block (a)
constexpr int BK = 64;   // k-chunk
constexpr int XS_STRIDE = 17;   // [BK][BR+1]
constexpr int WS_STRIDE = 68;   // [BK][BC+4], keeps 16B align for b128 reads

constexpr int QP_ELEMS = B * LQ * A;              // 524288

// ---------------------------------------------------------------------------
// Combined projection GEMM — EXACT round-2/6/8 sync structure (post-timing
// proven 3x): loads at loop top, barrier, stage, barrier, compute.
// Changes vs round 8 (parameters/layout only, no sync edits):
//   * BR=16 (grid 1024, 4 blocks/CU) — thread owns 1 row x 4 cols.
//   * kp written in a-pair-interleaved layout [b][A/2][LK][2] so the score
//     kernel loads ek for (a,a+1) as one aligned float2.
// Outputs are pre-exponentiated:
//   eq[row][a] = 2^(qproj*2log2e),  ek[b][a][k] = 2^(kproj*2log2e)
// ---------------------------------------------------------------------------
__global__ __launch_bounds__(256) void proj_gemm(const float* __restrict__ Q,
                                                 const float* __restrict__ Kin,
                                                 const float* __restrict__ W1,
                                                 const float* __restrict__ W2,
                                                 float* __restrict__ qp,
                                                 float* __restrict__ kp) {
    __shared__ float Xs[BK][XS_STRIDE];  // [k][r]  (transposed X tile)
    __shared__ float Ws[BK][WS_STRIDE];  // [k][c]  (transposed W tile, pre-scaled)

    const int t       = threadIdx.x;
    const int tile_c  = blockIdx.x & 3;        // 4 col tiles (A=256 / BC=64)
    const int tile_r  = blockIdx.x >> 2;       // 256 row tiles
    const int rowbase = tile_r * BR;           // 0..4080
    const bool isQ    = rowbase < 2048;

    const float* X = isQ ? (Q   + (size_t)rowbase * D)
                         : (Kin + (size_t)(rowbase - 2048) * D);
    const float* W = (isQ ? W1 : W2) + (size_t)(tile_c * BC) * D;

    // staging maps (coalesced global reads)
    const int sx_r = t >> 4;            // 0..15 (row within X tile)
    const int sx_k = (t & 15) * 4;      // 0..60 (k offset, 4 floats per thread)
    const int sw_c = t >> 2;            // 0..63 (a within W tile)
    const int sw_k = (t & 3) * 16;      // 0,16,32,48 (16 floats per thread)

    // compute maps: thread owns 1 row x 4 cols
    const int cg = t & 15, rg = t >> 4;
    const int c0 = cg * 4, r0 = rg;

    float acc[4] = {};

    for (int k0 = 0; k0 < D; k0 += BK) {
        // issue global loads early
        const float* xptr = X + (size_t)sx_r * D + k0 + sx_k;
        float4 xa = *(const float4*)(xptr);
        const float* wptr = W + (size_t)sw_c * D + k0 + sw_k;
        float4 wv0 = *(const float4*)(wptr);
        float4 wv1 = *(const float4*)(wptr + 4);
        float4 wv2 = *(const float4*)(wptr + 8);
        float4 wv3 = *(const float4*)(wptr + 12);

        __syncthreads();  // previous chunk's compute done before overwrite

        Xs[sx_k + 0][sx_r] = xa.x;
        Xs[sx_k + 1][sx_r] = xa.y;
        Xs[sx_k + 2][sx_r] = xa.z;
        Xs[sx_k + 3][sx_r] = xa.w;

        Ws[sw_k +  0][sw_c] = wv0.x * TWO_LOG2E;
        Ws[sw_k +  1][sw_c] = wv0.y * TWO_LOG2E;
        Ws[sw_k +  2][sw_c] = wv0.z * TWO_LOG2E;
        Ws[sw_k +  3][sw_c] = wv0.w * TWO_LOG2E;
        Ws[sw_k +  4][sw_c] = wv1.x * TWO_LOG2E;
        Ws[sw_k +  5][sw_c] = wv1.y * TWO_LOG2E;
        Ws[sw_k +  6][sw_c] = wv1.z * TWO_LOG2E;
        Ws[sw_k +  7][sw_c] = wv1.w * TWO_LOG2E;
        Ws[sw_k +  8][sw_c] = wv2.x * TWO_LOG2E;
        Ws[sw_k +  9][sw_c] = wv2.y * TWO_LOG2E;
        Ws[sw_k + 10][sw_c] = wv2.z * TWO_LOG2E;
        Ws[sw_k + 11][sw_c] = wv2.w * TWO_LOG2E;
        Ws[sw_k + 12][sw_c] = wv3.x * TWO_LOG2E;
        Ws[sw_k + 13][sw_c] = wv3.y * TWO_LOG2E;
        Ws[sw_k + 14][sw_c] = wv3.z * TWO_LOG2E;
        Ws[sw_k + 15][sw_c] = wv3.w * TWO_LOG2E;

        __syncthreads();

#pragma unroll 8
        for (int kk = 0; kk < BK; ++kk) {
            float  xr = Xs[kk][r0];                   // broadcast within group
            float4 wr = *(const float4*)&Ws[kk][c0];
            acc[0] = fmaf(xr, wr.x, acc[0]);
            acc[1] = fmaf(xr, wr.y, acc[1]);
            acc[2] = fmaf(xr, wr.z, acc[2]);
            acc[3] = fmaf(xr, wr.w, acc[3]);
        }
    }

    // epilogue: exponentiate (register-private; sync structure untouched)
#pragma unroll
    for (int j = 0; j < 4; ++j)
        acc[j] = __builtin_amdgcn_exp2f(acc[j]);

    const int cbase = tile_c * BC;
    if (isQ) {
        float4 v = make_float4(acc[0], acc[1], acc[2], acc[3]);
        *(float4*)(qp + (size_t)(rowbase + r0) * A + cbase + c0) = v;
    } else {
        // transpose 16x64 tile through LDS, write kp a-pair-interleaved:
        // kp[b][a>>1][k][a&1], coalesced-ish along k
        __syncthreads();   // last compute reads of Xs done before overwrite
        float* T = &Xs[0][0];  // needs 64*17 = 1088 floats = Xs capacity
#pragma unroll
        for (int j = 0; j < 4; ++j)
            T[(c0 + j) * XS_STRIDE + r0] = acc[j];
        __syncthreads();

        const int bb    = (rowbase - 2048) >> 8;
        const int kbase = rowbase & 255;          // multiple of 16
        const int kk    = t & 15;                 // k within tile
        const int ag    = t >> 4;                 // 0..15
        float* dstb = kp + (size_t)bb * A * LK;
#pragma unroll
        for (int j = 0; j < 4; ++j) {
            int a2 = ag + 16 * j;                 // 0..63
            int a  = cbase + a2;
            dstb[((size_t)(a >> 1) * LK + kbase + kk) * 2 + (a & 1)] =
                T[a2 * XS_STRIDE + kk];
        }
    }
}

// ---------------------------------------------------------------------------
// Fused score + mask + softmax — EXACT round-3/6/8 sync structure (post-timing
// proven 3x). Change vs round 8 (layout only): ek loaded as float2 for the
// (a,a+1) pair from the interleaved kpT; two independent rcp chains per iter.
// score'[q][k] = -2 * sum_a w3[a] / (1 + eq[q][a]*ek[a][k])
// (row-constant sum(w3) dropped: softmax-invariant)
// ---------------------------------------------------------------------------
__global__ __launch_bounds__(256) void score_softmax(const float* __restrict__ qp,
                                                     const float* __restrict__ kpT,
                                                     const int* __restrict__ mask,
                                                     const float* __restrict__ w3,
                                                     float* __restrict__ out) {
    const int t    = threadIdx.x;            // k
    const int row0 = blockIdx.x * 2;         // global q-row
    const int b    = row0 >> 8;

    const float* kpb = kpT + (size_t)b * A * LK;   // [A/2][LK][2] interleaved
    const float* q0  = qp + (size_t)row0 * A;

    float acc0 = 0.f, acc1 = 0.f;

#pragma unroll 8
    for (int a = 0; a < A; a += 2) {
        float2 ek = *(const float2*)(kpb + ((size_t)(a >> 1) * LK + t) * 2);
        float w0  = w3[a], w1 = w3[a + 1];             // uniform -> s_load
        float q00 = q0[a],     q01 = q0[a + 1];        // uniform -> s_load
        float q10 = q0[A + a], q11 = q0[A + a + 1];
        float e00 = q00 * ek.x, e01 = q01 * ek.y;
        float e10 = q10 * ek.x, e11 = q11 * ek.y;
        float a00 = 1.0f + e00, a01 = 1.0f + e01;
        float a10 = 1.0f + e10, a11 = 1.0f + e11;
        float rp0 = __builtin_amdgcn_rcpf(a00 * a10);  // share across rows @ a
        float rp1 = __builtin_amdgcn_rcpf(a01 * a11);  // share across rows @ a+1
        acc0 = fmaf(a10 * rp0, w0, acc0);
        acc1 = fmaf(a00 * rp0, w0, acc1);
        acc0 = fmaf(a11 * rp1, w1, acc0);
        acc1 = fmaf(a01 * rp1, w1, acc1);
    }

    // mask + the -2 scale (applied once, preserves softmax ordering)
    const int* mrow = mask + (size_t)row0 * LK;
    float sc0 = (mrow[t]      == 0) ? NEG_INF : -2.0f * acc0;
    float sc1 = (mrow[LK + t] == 0) ? NEG_INF : -2.0f * acc1;

    // block softmax over 256 threads (4 waves), 2 rows
    __shared__ float red[2][8];
    const int wave = t >> 6, lane = t & 63;

    float m0 = sc0, m1 = sc1;
#pragma unroll
    for (int off = 32; off > 0; off >>= 1) {
        m0 = fmaxf(m0, __shfl_xor(m0, off));
        m1 = fmaxf(m1, __shfl_xor(m1, off));
    }
    if (lane == 0) { red[0][wave] = m0; red[1][wave] = m1; }
    __syncthreads();
    float rmax0 = fmaxf(fmaxf(red[0][0], red[0][1]), fmaxf(red[0][2], red[0][3]));
    float rmax1 = fmaxf(fmaxf(red[1][0], red[1][1]), fmaxf(red[1][2], red[1][3]));
    __syncthreads();

    float p0 = __builtin_amdgcn_exp2f((sc0 - rmax0) * LOG2E);
    float p1 = __builtin_amdgcn_exp2f((sc1 - rmax1) * LOG2E);

    float s0 = p0, s1 = p1;
#pragma unroll
    for (int off = 32; off > 0; off >>= 1) {
        s0 += __shfl_xor(s0, off);
        s1 += __shfl_xor(s1, off);
    }
    if (lane == 0) { red[0][wave] = s0; red[1][wave] = s1; }
    __syncthreads();
    float sum0 = (red[0][0] + red[0][1]) + (red[0][2] + red[0][3]);
    float sum1 = (red[1][0] + red[1][1]) + (red[1][2] + red[1][3]);

    out[(size_t)row0 * LK + t]       = p0 * __builtin_amdgcn_rcpf(sum0);
    out[(size_t)(row0 + 1) * LK + t] = p1 * __builtin_amdgcn_rcpf(sum1);
}

extern "C" void kernel_launch(void* const* d_in, const int* in_sizes, int n_in,
                              void* d_out, int out_size, void* d_ws, size_t ws_size,
                              hipStream_t stream) {
    const float* Q    = (const float*)d_in[0];   // [B,LQ,1,D]
    const float* K    = (const float*)d_in[1];   // [B,1,LK,D]
    const int*   mask = (const int*)d_in[2];     // [B,LQ,LK]
    const float* W1   = (const float*)d_in[3];   // [A,D]
    const float* W2   = (const float*)d_in[4];   // [A,D]
    const float* w3   = (const float*)d_in[5];   // [A]
    float* out = (float*)d_out;

    float* ws  = (float*)d_ws;
    float* qp  = ws;                     // [B*LQ][A]       eq = 2^(qproj*2log2e)
    float* kpT = ws + QP_ELEMS;          // [B][A/2][LK][2] ek = 2^(kproj*2log2e)

    proj_gemm<<<1024, 256, 0, stream>>>(Q, K, W1, W2, qp, kpT);
    score_softmax<<<(B * LQ) / 2, 256, 0, stream>>>(qp, kpT, mask, w3, out);
}

// Round 10
// 49.584 us; speedup vs baseline: 1.2178x; 1.2178x over previous
//
#include <hip/hip_runtime.h>
#include <hip/hip_bf16.h>
#include <cstdint>

// Problem dims (fixed by reference)
constexpr int B  = 8;
constexpr int LQ = 256;
constexpr int LK = 256;
constexpr int D  = 512;   // Dq == Dk
constexpr int A  = 256;

constexpr float NEG_INF   = -1e15f;               // matches reference -INFINITY
constexpr float LOG2E     = 1.4426950408889634f;
constexpr float TWO_LOG2E = 2.8853900817779268f;  // folded into W at staging

// GEMM tiling — round-8 proven parameters
constexpr int BR = 32;   // rows per block (q/k rows)
constexpr int BC = 64;   // cols per block (a)
constexpr int BK = 64;   // k-chunk
constexpr int XS_STRIDE = 34;
constexpr int WS_STRIDE = 68;

constexpr int QP_ELEMS = B * LQ * A;              // 524288

// ---------------------------------------------------------------------------
// Combined projection GEMM — EXACT round-8 kernel (post-timing proven), with
// ONE delta: the kp global-scatter addresses emit the a-pair-interleaved
// layout [b][A/2][LK][2] (epilogue address arithmetic only; staging, compute,
// LDS transpose and every barrier byte-identical to round 8).
// Outputs are pre-exponentiated:
//   eq[row][a] = 2^(qproj*2log2e),  ek[b][a>>1][k][a&1] = 2^(kproj*2log2e)
// ---------------------------------------------------------------------------
__global__ __launch_bounds__(256) void proj_gemm(const float* __restrict__ Q,
                                                 const float* __restrict__ Kin,
                                                 const float* __restrict__ W1,
                                                 const float* __restrict__ W2,
                                                 float* __restrict__ qp,
                                                 float* __restrict__ kp) {
    __shared__ float Xs[BK][XS_STRIDE];  // [k][r]  (transposed X tile)
    __shared__ float Ws[BK][WS_STRIDE];  // [k][c]  (transposed W tile, pre-scaled)

    const int t       = threadIdx.x;
    const int tile_c  = blockIdx.x & 3;        // 4 col tiles (A=256 / BC=64)
    const int tile_r  = blockIdx.x >> 2;       // 128 row tiles
    const int rowbase = tile_r * BR;           // 0..4064
    const bool isQ    = rowbase < 2048;

    const float* X = isQ ? (Q   + (size_t)rowbase * D)
                         : (Kin + (size_t)(rowbase - 2048) * D);
    const float* W = (isQ ? W1 : W2) + (size_t)(tile_c * BC) * D;

    // staging maps (coalesced global reads)
    const int sx_r = t >> 3;            // 0..31 (row within X tile)
    const int sx_k = (t & 7) * 8;       // 0..56 (k offset, 8 floats per thread)
    const int sw_c = t >> 2;            // 0..63 (a within W tile)
    const int sw_k = (t & 3) * 16;      // 0,16,32,48 (16 floats per thread)

    // compute maps: thread owns 2 rows x 4 cols
    const int cg = t & 15, rg = t >> 4;
    const int c0 = cg * 4, r0 = rg * 2;

    float acc[2][4] = {};

    for (int k0 = 0; k0 < D; k0 += BK) {
        // issue global loads early
        const float* xptr = X + (size_t)sx_r * D + k0 + sx_k;
        float4 xa = *(const float4*)(xptr);
        float4 xb = *(const float4*)(xptr + 4);
        const float* wptr = W + (size_t)sw_c * D + k0 + sw_k;
        float4 wv0 = *(const float4*)(wptr);
        float4 wv1 = *(const float4*)(wptr + 4);
        float4 wv2 = *(const float4*)(wptr + 8);
        float4 wv3 = *(const float4*)(wptr + 12);

        __syncthreads();  // previous chunk's compute done before overwrite

        Xs[sx_k + 0][sx_r] = xa.x;
        Xs[sx_k + 1][sx_r] = xa.y;
        Xs[sx_k + 2][sx_r] = xa.z;
        Xs[sx_k + 3][sx_r] = xa.w;
        Xs[sx_k + 4][sx_r] = xb.x;
        Xs[sx_k + 5][sx_r] = xb.y;
        Xs[sx_k + 6][sx_r] = xb.z;
        Xs[sx_k + 7][sx_r] = xb.w;

        Ws[sw_k +  0][sw_c] = wv0.x * TWO_LOG2E;
        Ws[sw_k +  1][sw_c] = wv0.y * TWO_LOG2E;
        Ws[sw_k +  2][sw_c] = wv0.z * TWO_LOG2E;
        Ws[sw_k +  3][sw_c] = wv0.w * TWO_LOG2E;
        Ws[sw_k +  4][sw_c] = wv1.x * TWO_LOG2E;
        Ws[sw_k +  5][sw_c] = wv1.y * TWO_LOG2E;
        Ws[sw_k +  6][sw_c] = wv1.z * TWO_LOG2E;
        Ws[sw_k +  7][sw_c] = wv1.w * TWO_LOG2E;
        Ws[sw_k +  8][sw_c] = wv2.x * TWO_LOG2E;
        Ws[sw_k +  9][sw_c] = wv2.y * TWO_LOG2E;
        Ws[sw_k + 10][sw_c] = wv2.z * TWO_LOG2E;
        Ws[sw_k + 11][sw_c] = wv2.w * TWO_LOG2E;
        Ws[sw_k + 12][sw_c] = wv3.x * TWO_LOG2E;
        Ws[sw_k + 13][sw_c] = wv3.y * TWO_LOG2E;
        Ws[sw_k + 14][sw_c] = wv3.z * TWO_LOG2E;
        Ws[sw_k + 15][sw_c] = wv3.w * TWO_LOG2E;

        __syncthreads();

#pragma unroll 8
        for (int kk = 0; kk < BK; ++kk) {
            float2 xr = *(const float2*)&Xs[kk][r0];
            float4 wr = *(const float4*)&Ws[kk][c0];
            acc[0][0] = fmaf(xr.x, wr.x, acc[0][0]);
            acc[0][1] = fmaf(xr.x, wr.y, acc[0][1]);
            acc[0][2] = fmaf(xr.x, wr.z, acc[0][2]);
            acc[0][3] = fmaf(xr.x, wr.w, acc[0][3]);
            acc[1][0] = fmaf(xr.y, wr.x, acc[1][0]);
            acc[1][1] = fmaf(xr.y, wr.y, acc[1][1]);
            acc[1][2] = fmaf(xr.y, wr.z, acc[1][2]);
            acc[1][3] = fmaf(xr.y, wr.w, acc[1][3]);
        }
    }

    // epilogue: exponentiate (register-private; sync structure untouched)
#pragma unroll
    for (int i = 0; i < 2; ++i)
#pragma unroll
        for (int j = 0; j < 4; ++j)
            acc[i][j] = __builtin_amdgcn_exp2f(acc[i][j]);

    const int cbase = tile_c * BC;
    if (isQ) {
#pragma unroll
        for (int i = 0; i < 2; ++i) {
            float4 v = make_float4(acc[i][0], acc[i][1], acc[i][2], acc[i][3]);
            *(float4*)(qp + (size_t)(rowbase + r0 + i) * A + cbase + c0) = v;
        }
    } else {
        // transpose 32x64 tile through LDS, then scatter to the
        // a-pair-interleaved layout kp[b][a>>1][k][a&1]
        __syncthreads();
        float* T = &Xs[0][0];  // 64*34 floats, exactly Xs capacity
#pragma unroll
        for (int i = 0; i < 2; ++i)
#pragma unroll
            for (int j = 0; j < 4; ++j)
                T[(c0 + j) * XS_STRIDE + (r0 + i)] = acc[i][j];
        __syncthreads();

        const int bb    = (rowbase - 2048) >> 8;
        const int kbase = rowbase & 255;          // multiple of 32
        const int kk    = t & 31;                 // k within tile
        const int ag    = t >> 5;                 // 0..7
        float* dstb = kp + (size_t)bb * A * LK;
#pragma unroll
        for (int j = 0; j < 8; ++j) {
            int a2 = ag + 8 * j;                  // 0..63
            int a  = cbase + a2;
            dstb[((size_t)(a >> 1) * LK + kbase + kk) * 2 + (a & 1)] =
                T[a2 * XS_STRIDE + kk];
        }
    }
}

// ---------------------------------------------------------------------------
// Fused score + mask + softmax — EXACT round-9 kernel (post-timing proven):
// float2 interleaved ek loads, two independent shared-rcp chains per iter.
// score'[q][k] = -2 * sum_a w3[a] / (1 + eq[q][a]*ek[a][k])
// (row-constant sum(w3) dropped: softmax-invariant)
// ---------------------------------------------------------------------------
__global__ __launch_bounds__(256) void score_softmax(const float* __restrict__ qp,
                                                     const float* __restrict__ kpT,
                                                     const int* __restrict__ mask,
                                                     const float* __restrict__ w3,
                                                     float* __restrict__ out) {
    const int t    = threadIdx.x;            // k
    const int row0 = blockIdx.x * 2;         // global q-row
    const int b    = row0 >> 8;

    const float* kpb = kpT + (size_t)b * A * LK;   // [A/2][LK][2] interleaved
    const float* q0  = qp + (size_t)row0 * A;

    float acc0 = 0.f, acc1 = 0.f;

#pragma unroll 8
    for (int a = 0; a < A; a += 2) {
        float2 ek = *(const float2*)(kpb + ((size_t)(a >> 1) * LK + t) * 2);
        float w0  = w3[a], w1 = w3[a + 1];             // uniform -> s_load
        float q00 = q0[a],     q01 = q0[a + 1];        // uniform -> s_load
        float q10 = q0[A + a], q11 = q0[A + a + 1];
        float e00 = q00 * ek.x, e01 = q01 * ek.y;
        float e10 = q10 * ek.x, e11 = q11 * ek.y;
        float a00 = 1.0f + e00, a01 = 1.0f + e01;
        float a10 = 1.0f + e10, a11 = 1.0f + e11;
        float rp0 = __builtin_amdgcn_rcpf(a00 * a10);  // share across rows @ a
        float rp1 = __builtin_amdgcn_rcpf(a01 * a11);  // share across rows @ a+1
        acc0 = fmaf(a10 * rp0, w0, acc0);
        acc1 = fmaf(a00 * rp0, w0, acc1);
        acc0 = fmaf(a11 * rp1, w1, acc0);
        acc1 = fmaf(a01 * rp1, w1, acc1);
    }

    // mask + the -2 scale (applied once, preserves softmax ordering)
    const int* mrow = mask + (size_t)row0 * LK;
    float sc0 = (mrow[t]      == 0) ? NEG_INF : -2.0f * acc0;
    float sc1 = (mrow[LK + t] == 0) ? NEG_INF : -2.0f * acc1;

    // block softmax over 256 threads (4 waves), 2 rows
    __shared__ float red[2][8];
    const int wave = t >> 6, lane = t & 63;

    float m0 = sc0, m1 = sc1;
#pragma unroll
    for (int off = 32; off > 0; off >>= 1) {
        m0 = fmaxf(m0, __shfl_xor(m0, off));
        m1 = fmaxf(m1, __shfl_xor(m1, off));
    }
    if (lane == 0) { red[0][wave] = m0; red[1][wave] = m1; }
    __syncthreads();
    float rmax0 = fmaxf(fmaxf(red[0][0], red[0][1]), fmaxf(red[0][2], red[0][3]));
    float rmax1 = fmaxf(fmaxf(red[1][0], red[1][1]), fmaxf(red[1][2], red[1][3]));
    __syncthreads();

    float p0 = __builtin_amdgcn_exp2f((sc0 - rmax0) * LOG2E);
    float p1 = __builtin_amdgcn_exp2f((sc1 - rmax1) * LOG2E);

    float s0 = p0, s1 = p1;
#pragma unroll
    for (int off = 32; off > 0; off >>= 1) {
        s0 += __shfl_xor(s0, off);
        s1 += __shfl_xor(s1, off);
    }
    if (lane == 0) { red[0][wave] = s0; red[1][wave] = s1; }
    __syncthreads();
    float sum0 = (red[0][0] + red[0][1]) + (red[0][2] + red[0][3]);
    float sum1 = (red[1][0] + red[1][1]) + (red[1][2] + red[1][3]);

    out[(size_t)row0 * LK + t]       = p0 * __builtin_amdgcn_rcpf(sum0);
    out[(size_t)(row0 + 1) * LK + t] = p1 * __builtin_amdgcn_rcpf(sum1);
}

extern "C" void kernel_launch(void* const* d_in, const int* in_sizes, int n_in,
                              void* d_out, int out_size, void* d_ws, size_t ws_size,
                              hipStream_t stream) {
    const float* Q    = (const float*)d_in[0];   // [B,LQ,1,D]
    const float* K    = (const float*)d_in[1];   // [B,1,LK,D]
    const int*   mask = (const int*)d_in[2];     // [B,LQ,LK]
    const float* W1   = (const float*)d_in[3];   // [A,D]
    const float* W2   = (const float*)d_in[4];   // [A,D]
    const float* w3   = (const float*)d_in[5];   // [A]
    float* out = (float*)d_out;

    float* ws  = (float*)d_ws;
    float* qp  = ws;                     // [B*LQ][A]       eq = 2^(qproj*2log2e)
    float* kpT = ws + QP_ELEMS;          // [B][A/2][LK][2] ek = 2^(kproj*2log2e)

    proj_gemm<<<512, 256, 0, stream>>>(Q, K, W1, W2, qp, kpT);
    score_softmax<<<(B * LQ) / 2, 256, 0, stream>>>(qp, kpT, mask, w3, out);
}